// Round 14
// baseline (34.748 us; speedup 1.0000x reference)
//
#include <hip/hip_runtime.h>
#include <math.h>

#define NATOMS 32
#define NMOL   64
#define MAXP   466     // >= C(31,2)=465
#define RCRf 5.2f
#define RCAf 3.5f

// DIAGNOSTIC ROUND: exact R12 kernel, but grid x4 (8192 blocks); the 4
// replicas of each center compute and write IDENTICAL values (benign).
// Purpose: split bench dur into 4*kernel + overhead, and push aev_kernel
// above the harness's 39us fill dispatches so rocprof shows its counters.
__global__ __launch_bounds__(512) void aev_kernel(const int* __restrict__ species,
                                                  const float* __restrict__ coords,
                                                  float* __restrict__ out) {
    const int bid = blockIdx.x & 2047;           // 4 replicas per center
    const int n = bid >> 5;
    const int i = bid & 31;
    const int tid = threadIdx.x;

    __shared__ float4 s_atom[NATOMS];            // dx, dy, dz, d
    __shared__ float2 s_dfr[NATOMS];             // d, fcr (radial)
    __shared__ float  s_fca[NATOMS];
    __shared__ int    s_sp[NATOMS];
    __shared__ int    s_nbr[NATOMS];
    __shared__ int    s_nn;
    __shared__ __align__(16) float s_rec[MAXP*12];   // f1[0..7], f2f[0..3]
    __shared__ int    s_cnt[10], s_rank[10];

    // ---------- phase A ----------
    if (tid < 10) { s_cnt[tid] = 0; s_rank[tid] = 0; }
    if (tid < 64) {
        float fca_v = 0.f;
        if (tid < NATOMS) {
            const float* cb = coords + (size_t)n*NATOMS*3;
            float dx = cb[tid*3+0] - cb[i*3+0];
            float dy = cb[tid*3+1] - cb[i*3+1];
            float dz = cb[tid*3+2] - cb[i*3+2];
            float d2 = dx*dx + dy*dy + dz*dz;
            float d  = sqrtf(d2 > 0.f ? d2 : 1.f);   // ref's where(d2>0,d2,1) guard
            bool self = (tid == i);
            float fr = (!self && d <= RCRf) ? (0.5f*__cosf(((float)M_PI/RCRf)*d) + 0.5f) : 0.f;
            fca_v    = (!self && d <= RCAf) ? (0.5f*__cosf(((float)M_PI/RCAf)*d) + 0.5f) : 0.f;
            s_atom[tid] = make_float4(dx, dy, dz, d);
            s_dfr[tid]  = make_float2(d, fr);
            s_fca[tid]  = fca_v;
            s_sp[tid]   = species[n*NATOMS + tid];
        }
        unsigned long long m = __ballot(fca_v > 0.f);  // full-wave-active context
        if (fca_v > 0.f) s_nbr[__popcll(m & ((1ull << tid) - 1ull))] = tid;
        if (tid == 0) s_nn = (int)__popcll(m);
    }
    __syncthreads();                                   // barrier 1

    const int nn  = s_nn;
    const int cnt = (nn*(nn-1)) >> 1;                  // <= 465 < 512: single pass
    const int M   = 2*nn - 1;

    const float CZ[8] = { 0.98078528f,  0.83146961f,  0.55557023f,  0.19509032f,
                         -0.19509032f, -0.55557023f, -0.83146961f, -0.98078528f};
    const float SZ[8] = { 0.19509032f,  0.55557023f,  0.83146961f,  0.98078528f,
                          0.98078528f,  0.83146961f,  0.55557023f,  0.19509032f};
    const float SHA[4] = {0.9f, 1.55f, 2.2f, 2.85f};

    // ---------- phase B: record build in registers + histogram ----------
    int px = -1;
    float4 v0, v1, v2;
    if (tid < cnt) {
        float t = sqrtf((float)(M*M - 8*tid));
        int jj = (int)(((float)M - t) * 0.5f);
        jj = max(0, min(jj, nn-2));
        while (jj*(2*nn-jj-1)/2 > tid) --jj;           // <=2 fixup steps
        while ((jj+1)*(2*nn-jj-2)/2 <= tid) ++jj;
        int kk = tid - jj*(2*nn-jj-1)/2 + jj + 1;
        int j = s_nbr[jj], k = s_nbr[kk];
        float4 aj = s_atom[j], ak = s_atom[k];
        float fc2 = 2.f * s_fca[j] * s_fca[k];
        float dot = aj.x*ak.x + aj.y*ak.y + aj.z*ak.z;
        float c = 0.95f * dot * __builtin_amdgcn_rcpf(aj.w * ak.w);
        c = fminf(0.95f, fmaxf(-0.95f, c));
        float s = sqrtf(1.f - c*c);                    // sin(acos(c))
        float dmean = 0.5f * (aj.w + ak.w);
        int sj = s_sp[j], sk = s_sp[k];
        int lo = min(sj, sk), hi = max(sj, sk);
        px = ((lo*(9-lo)) >> 1) + (hi - lo);           // triu pair index, S=4
        v0.x = 0.5f + 0.5f*(c*CZ[0] + s*SZ[0]);
        v0.y = 0.5f + 0.5f*(c*CZ[1] + s*SZ[1]);
        v0.z = 0.5f + 0.5f*(c*CZ[2] + s*SZ[2]);
        v0.w = 0.5f + 0.5f*(c*CZ[3] + s*SZ[3]);
        v1.x = 0.5f + 0.5f*(c*CZ[4] + s*SZ[4]);
        v1.y = 0.5f + 0.5f*(c*CZ[5] + s*SZ[5]);
        v1.z = 0.5f + 0.5f*(c*CZ[6] + s*SZ[6]);
        v1.w = 0.5f + 0.5f*(c*CZ[7] + s*SZ[7]);
        #define POW32(q) { q = q*q; q = q*q; q = q*q; q = q*q; q = q*q; }
        POW32(v0.x) POW32(v0.y) POW32(v0.z) POW32(v0.w)
        POW32(v1.x) POW32(v1.y) POW32(v1.z) POW32(v1.w)
        #undef POW32
        float dm0 = dmean - SHA[0], dm1 = dmean - SHA[1];
        float dm2 = dmean - SHA[2], dm3 = dmean - SHA[3];
        v2.x = __expf(-8.f*dm0*dm0) * fc2;
        v2.y = __expf(-8.f*dm1*dm1) * fc2;
        v2.z = __expf(-8.f*dm2*dm2) * fc2;
        v2.w = __expf(-8.f*dm3*dm3) * fc2;
        atomicAdd(&s_cnt[px], 1);
    }
    __syncthreads();                                   // barrier 2

    // counts complete: every thread reads them (broadcast) for prefix math
    int c0 = s_cnt[0], c1 = s_cnt[1], c2 = s_cnt[2], c3 = s_cnt[3], c4 = s_cnt[4];
    int c5 = s_cnt[5], c6 = s_cnt[6], c7 = s_cnt[7], c8 = s_cnt[8], c9 = s_cnt[9];

    // ---------- phase C: slot = prefix + rank; write record ----------
    if (px >= 0) {
        int base = 0;
        base += (px > 0) ? c0 : 0;  base += (px > 1) ? c1 : 0;
        base += (px > 2) ? c2 : 0;  base += (px > 3) ? c3 : 0;
        base += (px > 4) ? c4 : 0;  base += (px > 5) ? c5 : 0;
        base += (px > 6) ? c6 : 0;  base += (px > 7) ? c7 : 0;
        base += (px > 8) ? c8 : 0;
        int slot = base + atomicAdd(&s_rank[px], 1);
        float* r = &s_rec[slot*12];
        *(float4*)(r+0) = v0;
        *(float4*)(r+4) = v1;
        *(float4*)(r+8) = v2;
    }
    __syncthreads();                                   // barrier 3

    // ---------- phase E ----------
    float* oa = out + NMOL*NATOMS + (size_t)bid * 384;

    if (tid < 320) {
        const int b = tid >> 5;
        const int a = (tid >> 3) & 3;
        const int z = tid & 7;
        int base = 0;
        base += (b > 0) ? c0 : 0;  base += (b > 1) ? c1 : 0;
        base += (b > 2) ? c2 : 0;  base += (b > 3) ? c3 : 0;
        base += (b > 4) ? c4 : 0;  base += (b > 5) ? c5 : 0;
        base += (b > 6) ? c6 : 0;  base += (b > 7) ? c7 : 0;
        base += (b > 8) ? c8 : 0;
        int bc = b==0?c0 : b==1?c1 : b==2?c2 : b==3?c3 : b==4?c4
               : b==5?c5 : b==6?c6 : b==7?c7 : b==8?c8 : c9;
        float acc = 0.f;
        #pragma unroll 4
        for (int q = base; q < base + bc; ++q)
            acc += s_rec[q*12 + z] * s_rec[q*12 + 8 + a];
        oa[64 + tid] = acc;
        if (tid == 0) out[bid] = (float)s_sp[i];       // output 0: species
    } else if (tid < 384) {
        const int f  = tid - 320;
        const int rs = f >> 4;
        const float shr = 0.9f + 0.26875f * (float)(f & 15);   // SHF_R
        float racc = 0.f;
        #pragma unroll 8
        for (int j = 0; j < NATOMS; ++j) {
            float2 dfr = s_dfr[j];                     // fr==0 encodes mask
            float dmr = dfr.x - shr;
            racc += (s_sp[j] == rs) ? 0.25f * __expf(-16.f*dmr*dmr) * dfr.y : 0.f;
        }
        oa[f] = racc;
    }
}

extern "C" void kernel_launch(void* const* d_in, const int* in_sizes, int n_in,
                              void* d_out, int out_size, void* d_ws, size_t ws_size,
                              hipStream_t stream) {
    const int*   species = (const int*)d_in[0];
    const float* coords  = (const float*)d_in[1];
    float*       out     = (float*)d_out;
    aev_kernel<<<NMOL * NATOMS * 4, 512, 0, stream>>>(species, coords, out);
}

// Round 15
// 16.396 us; speedup vs baseline: 2.1193x; 2.1193x over previous
//
#include <hip/hip_runtime.h>
#include <math.h>

#define NATOMS 32
#define NMOL   64
#define MAXPC  465     // C(31,2) per center
#define RCRf 5.2f
#define RCAf 3.5f

// 512 blocks x 512 threads; block = (mol = blk>>3, 4 centers i0..i0+3).
// All per-center phases run in PARALLEL across thread groups:
//  A  (tid<128): entry (c=tid>>5, j=tid&31): dv/d/fc; per-half-wave ballot
//     compaction into s_catom[c]/s_cfs[c] (compact-indexed, no indirection).
//  B1 (c=tid>>7, 128 thr/center): decode pairs p=l+128*pass in compacted
//     space, histogram px into s_cnt[c].
//  B2: records {f1[0..7] as bf16 RTN pairs, f2f[0..3] f32} -> bucket-sorted
//     slot (prefix in regs + atomicAdd rank), 2x b128 writes. LDS 64.05KB.
//  E: 1280 angular slots (c,f) over 512 thr (2-3 each, bucket-scan: 2 LDS
//     reads + unpack + fma); radial 256 slots on tid>=256. 3 barriers.
__global__ __launch_bounds__(512) void aev_kernel(const int* __restrict__ species,
                                                  const float* __restrict__ coords,
                                                  float* __restrict__ out) {
    const int blk = blockIdx.x;
    const int mol = blk >> 3;
    const int i0  = (blk & 7) << 2;
    const int tid = threadIdx.x;
    const int lane = tid & 63;

    __shared__ float4   s_catom[4][NATOMS];      // compacted: dx,dy,dz,d
    __shared__ float2   s_cfs[4][NATOMS];        // compacted: fca, species
    __shared__ float2   s_dfr[4][NATOMS];        // orig idx: d, fcr (radial)
    __shared__ int      s_sp[NATOMS];
    __shared__ unsigned s_rec[4][MAXPC*8];       // 4 dw bf16-f1 + 4 dw f32-f2f
    __shared__ int      s_cnt[4][10], s_rank[4][10], s_nn[4];

    if (tid < 40)               ((int*)s_cnt)[tid]      = 0;
    else if (tid < 80)          ((int*)s_rank)[tid-40]  = 0;

    // ---------- phase A (tid<128): 4 centers in parallel ----------
    if (tid < 128) {
        const int c = tid >> 5, j = tid & 31, i = i0 + c;
        const float* cb = coords + (size_t)mol*NATOMS*3;
        float dx = cb[j*3+0] - cb[i*3+0];
        float dy = cb[j*3+1] - cb[i*3+1];
        float dz = cb[j*3+2] - cb[i*3+2];
        float d2 = dx*dx + dy*dy + dz*dz;
        float d  = sqrtf(d2 > 0.f ? d2 : 1.f);   // ref's where(d2>0,d2,1) guard
        int  spv = species[mol*NATOMS + j];
        bool self = (j == i);
        float fr  = (!self && d <= RCRf) ? (0.5f*__cosf(((float)M_PI/RCRf)*d) + 0.5f) : 0.f;
        float fca = (!self && d <= RCAf) ? (0.5f*__cosf(((float)M_PI/RCAf)*d) + 0.5f) : 0.f;
        s_dfr[c][j] = make_float2(d, fr);
        if (tid < 32) s_sp[j] = spv;
        // compaction: one wave holds 2 centers (lanes 0..31 / 32..63)
        unsigned long long m = __ballot(fca > 0.f);        // full-wave context
        unsigned mh = (unsigned)(m >> (lane & 32));        // this half's mask
        int lpos = lane & 31;
        int ci = __popc(mh & ((1u << lpos) - 1u));
        if (fca > 0.f) {
            s_catom[c][ci] = make_float4(dx, dy, dz, d);
            s_cfs[c][ci]   = make_float2(fca, (float)spv);
        }
        if (lpos == 0) s_nn[c] = __popc(mh);
    }
    __syncthreads();                                       // barrier 1

    const int c  = tid >> 7;                // this thread's center group
    const int l  = tid & 127;
    const int nn = s_nn[c];
    const int cnt = (nn*(nn-1)) >> 1;       // <= 465
    const int M   = 2*nn - 1;

    if (tid < 4) out[mol*NATOMS + i0 + tid] = (float)s_sp[i0 + tid];  // species

    // ---------- B1: decode + histogram (128 thr/center) ----------
    for (int p = l; p < cnt; p += 128) {
        float t = sqrtf((float)(M*M - 8*p));
        int jj = (int)(((float)M - t) * 0.5f);
        jj = max(0, min(jj, nn-2));
        while (jj*(2*nn-jj-1)/2 > p) --jj;
        while ((jj+1)*(2*nn-jj-2)/2 <= p) ++jj;
        int kk = p - jj*(2*nn-jj-1)/2 + jj + 1;
        int sj = (int)s_cfs[c][jj].y, sk = (int)s_cfs[c][kk].y;
        int lo = min(sj, sk), hi = max(sj, sk);
        int px = ((lo*(9-lo)) >> 1) + (hi - lo);           // triu pair index
        atomicAdd(&s_cnt[c][px], 1);
    }
    __syncthreads();                                       // barrier 2

    int cc[10], pf[10];
    {
        int run = 0;
        #pragma unroll
        for (int b = 0; b < 10; ++b) { cc[b] = s_cnt[c][b]; pf[b] = run; run += cc[b]; }
    }

    // ---------- B2: build + bucket-sorted place ----------
    const float CZ[8] = { 0.98078528f,  0.83146961f,  0.55557023f,  0.19509032f,
                         -0.19509032f, -0.55557023f, -0.83146961f, -0.98078528f};
    const float SZ[8] = { 0.19509032f,  0.55557023f,  0.83146961f,  0.98078528f,
                          0.98078528f,  0.83146961f,  0.55557023f,  0.19509032f};
    const float SHA[4] = {0.9f, 1.55f, 2.2f, 2.85f};

    for (int p = l; p < cnt; p += 128) {
        float t = sqrtf((float)(M*M - 8*p));
        int jj = (int)(((float)M - t) * 0.5f);
        jj = max(0, min(jj, nn-2));
        while (jj*(2*nn-jj-1)/2 > p) --jj;
        while ((jj+1)*(2*nn-jj-2)/2 <= p) ++jj;
        int kk = p - jj*(2*nn-jj-1)/2 + jj + 1;
        float4 aj = s_catom[c][jj], ak = s_catom[c][kk];
        float2 fj = s_cfs[c][jj],  fk = s_cfs[c][kk];
        float fc2 = 2.f * fj.x * fk.x;
        float dot = aj.x*ak.x + aj.y*ak.y + aj.z*ak.z;
        float cv = 0.95f * dot * __builtin_amdgcn_rcpf(aj.w * ak.w);
        cv = fminf(0.95f, fmaxf(-0.95f, cv));
        float sv = sqrtf(1.f - cv*cv);                     // sin(acos(c))
        float dmean = 0.5f * (aj.w + ak.w);
        int sj = (int)fj.y, sk = (int)fk.y;
        int lo = min(sj, sk), hi = max(sj, sk);
        int px = ((lo*(9-lo)) >> 1) + (hi - lo);
        float f1[8];
        #pragma unroll
        for (int z = 0; z < 8; ++z) {
            float x = 0.5f + 0.5f*(cv*CZ[z] + sv*SZ[z]);   // (1+cos(th-sz))/2
            float q = x*x; q *= q; q *= q; q *= q; q *= q; // ^32
            f1[z] = q;
        }
        uint4 u;                                           // bf16 RTN pairs
        u.x = ((__float_as_uint(f1[0]) + 0x8000u) >> 16) | (((__float_as_uint(f1[1]) + 0x8000u) >> 16) << 16);
        u.y = ((__float_as_uint(f1[2]) + 0x8000u) >> 16) | (((__float_as_uint(f1[3]) + 0x8000u) >> 16) << 16);
        u.z = ((__float_as_uint(f1[4]) + 0x8000u) >> 16) | (((__float_as_uint(f1[5]) + 0x8000u) >> 16) << 16);
        u.w = ((__float_as_uint(f1[6]) + 0x8000u) >> 16) | (((__float_as_uint(f1[7]) + 0x8000u) >> 16) << 16);
        float4 v2;
        float dm0 = dmean - SHA[0], dm1 = dmean - SHA[1];
        float dm2 = dmean - SHA[2], dm3 = dmean - SHA[3];
        v2.x = __expf(-8.f*dm0*dm0) * fc2;
        v2.y = __expf(-8.f*dm1*dm1) * fc2;
        v2.z = __expf(-8.f*dm2*dm2) * fc2;
        v2.w = __expf(-8.f*dm3*dm3) * fc2;
        int slot = pf[px] + atomicAdd(&s_rank[c][px], 1);
        unsigned* r = &s_rec[c][slot*8];
        *(uint4*)r        = u;
        *(float4*)(r + 4) = v2;
    }
    __syncthreads();                                       // barrier 3

    // ---------- E: feature ownership ----------
    float* outbase = out + NMOL*NATOMS;

    #pragma unroll
    for (int k = 0; k < 3; ++k) {
        int g = tid + (k << 9);
        if (g < 1280) {
            int ec = g / 320;
            int f  = g - ec*320;
            int b = f >> 5, a = (f >> 3) & 3, z = f & 7;
            int base = 0, bc;
            #pragma unroll
            for (int q = 0; q < 10; ++q) { int v = s_cnt[ec][q]; base += (q < b) ? v : 0; }
            bc = s_cnt[ec][b];
            const unsigned* rb = &s_rec[ec][0];
            const int zh = z >> 1, hi16 = (z & 1);
            float acc = 0.f;
            #pragma unroll 4
            for (int q = base; q < base + bc; ++q) {
                unsigned uf = rb[q*8 + zh];
                float f1 = __uint_as_float(hi16 ? (uf & 0xFFFF0000u) : (uf << 16));
                float f2 = __uint_as_float(rb[q*8 + 4 + a]);
                acc += f1 * f2;
            }
            outbase[(size_t)(mol*NATOMS + i0 + ec)*384 + 64 + f] = acc;
        }
    }

    if (tid >= 256) {                                      // radial: 4x64 slots
        int t = tid - 256;
        int rc = t >> 6, f = t & 63;
        int rs = f >> 4;
        float shr = 0.9f + 0.26875f * (float)(f & 15);     // SHF_R
        float racc = 0.f;
        #pragma unroll 8
        for (int j = 0; j < NATOMS; ++j) {
            float2 dfr = s_dfr[rc][j];                     // fr==0 encodes mask
            float dm = dfr.x - shr;
            racc += (s_sp[j] == rs) ? 0.25f * __expf(-16.f*dm*dm) * dfr.y : 0.f;
        }
        outbase[(size_t)(mol*NATOMS + i0 + rc)*384 + f] = racc;
    }
}

extern "C" void kernel_launch(void* const* d_in, const int* in_sizes, int n_in,
                              void* d_out, int out_size, void* d_ws, size_t ws_size,
                              hipStream_t stream) {
    const int*   species = (const int*)d_in[0];
    const float* coords  = (const float*)d_in[1];
    float*       out     = (float*)d_out;
    aev_kernel<<<NMOL*8, 512, 0, stream>>>(species, coords, out);
}